// Round 7
// baseline (143.438 us; speedup 1.0000x reference)
//
#include <hip/hip_runtime.h>
#include <hip/hip_bf16.h>

#define NDIM 128
#define BDIM 131072
#define NMZI 8128                       // 128*127/2
#define NCHUNK 8
#define CSTEP (NMZI / NCHUNK)           // 1016 steps per chunk
#define NJG 8                           // j-groups per block (scan groups)
#define NCOL 32                         // columns per block
#define NLOC 16                         // max local scan length
static constexpr float CC = 0.70710678118654752440f;  // sqrt(0.5)

typedef __attribute__((ext_vector_type(8))) short bf16x8;
typedef __attribute__((ext_vector_type(4))) float f32x4;

// Static device scratch (d_ws size unknown -> don't touch it)
__device__ __align__(16) float2         g_V[NCHUNK * NDIM * NDIM];  // chunk partial unitaries
__device__ __align__(16) float2         g_W[4 * NDIM * NDIM];       // compose level 1
__device__ __align__(16) float2         g_Y[2 * NDIM * NDIM];       // compose level 2
// Packed K=256 table for real-output GEMM: kg2<16 -> Ur[k=kg2*8+e][n]; kg2>=16 -> -Ui
__device__ __align__(16) unsigned short g_TB[32 * NDIM * 8];        // 64 KB
// Separate tables for the (unlikely) complex-interleaved output mode
__device__ __align__(16) unsigned short g_Ur[16 * NDIM * 8];
__device__ __align__(16) unsigned short g_Ui[16 * NDIM * 8];

__device__ inline unsigned short f2bf(float f) {
    union { __hip_bfloat16 h; unsigned short u; } cv;
    cv.h = __float2bfloat16(f);
    return cv.u;
}

// ---------------- K2: build chunk partial unitaries (affine-scan) ----------------
__global__ __launch_bounds__(256) void build_scan(const float* __restrict__ mzi) {
    __shared__ float2 Usm[NDIM][NCOL];        // 32 KB
    __shared__ float4 phs[CSTEP];             // 16.25 KB
    __shared__ float4 comp[NJG][NCOL];        // 4 KB
    const int tid   = threadIdx.x;
    const int c     = tid & 31;
    const int g     = tid >> 5;
    const int col0  = blockIdx.x * NCOL;
    const int chunk = blockIdx.y;
    const int s0 = chunk * CSTEP, s1 = s0 + CSTEP;

    for (int k = g; k < NDIM; k += NJG)
        Usm[k][c] = make_float2((k == col0 + c) ? 1.f : 0.f, 0.f);
    const float2* mzp = (const float2*)mzi;   // (theta, phi) pairs
    for (int t = tid; t < CSTEP; t += 256) {
        const float2 mz = mzp[s0 + t];
        float sp, cp, st, ct;
        sincosf(mz.y, &sp, &cp);              // phi
        sincosf(mz.x, &st, &ct);              // theta
        phs[t] = make_float4(cp, sp, CC * ct, CC * st);
    }
    __syncthreads();

    int i = 0, base = 0;
    while (base + (NDIM - 1 - i) <= s0) { base += NDIM - 1 - i; ++i; }

    int s = s0;
    while (s < s1) {
        const int cnt  = NDIM - 1 - i;
        const int jA   = i + 1 + (s - base);
        const int L    = min(s1, base + cnt) - s;
        const int nloc = (L + NJG - 1) >> 3;
        const int myBeg = g * nloc;
        const int myN   = max(0, min(nloc, L - myBeg));
        const int pbase = s - s0;

        const float2 r0 = Usm[i][c];          // read BEFORE barrier

        float2 treg[NLOC];
        float2 qth[NLOC];
        float  A = 1.f;
        float2 Bc = make_float2(0.f, 0.f);
        #pragma unroll
        for (int kk = 0; kk < NLOC; ++kk) {
            if (kk < myN) {
                const int off = myBeg + kk;
                const float4 q  = phs[pbase + off];
                const float2 rj = Usm[jA + off][c];
                const float tr = fmaf(q.x, rj.x, -q.y * rj.y);
                const float ti = fmaf(q.x, rj.y,  q.y * rj.x);
                treg[kk] = make_float2(tr, ti);
                qth[kk]  = make_float2(q.z, q.w);
                Bc.x = CC * (Bc.x + tr);
                Bc.y = CC * (Bc.y + ti);
                A *= CC;
            }
        }
        comp[g][c] = make_float4(A, Bc.x, Bc.y, 0.f);
        __syncthreads();

        float2 r = r0;
        for (int h = 0; h < g; ++h) {
            const float4 cm = comp[h][c];
            r.x = fmaf(cm.x, r.x, cm.y);
            r.y = fmaf(cm.x, r.y, cm.z);
        }

        #pragma unroll
        for (int kk = 0; kk < NLOC; ++kk) {
            if (kk < myN) {
                const float2 t = treg[kk];
                const float2 q = qth[kk];
                const float dr = r.x - t.x, di = r.y - t.y;
                const float njx = fmaf(q.x, dr, -q.y * di);
                const float njy = fmaf(q.x, di,  q.y * dr);
                Usm[jA + myBeg + kk][c] = make_float2(njx, njy);
                r.x = CC * (r.x + t.x);
                r.y = CC * (r.y + t.y);
            }
        }
        if (myN > 0 && (myBeg + myN == L))
            Usm[i][c] = r;
        __syncthreads();

        s += L;
        if (s == base + cnt) { base += cnt; ++i; }
    }

    float2* Vp = g_V + chunk * NDIM * NDIM;
    for (int k = g; k < NDIM; k += NJG)
        Vp[k * NDIM + col0 + c] = Usm[k][c];
}

// ---------------- K3: compose tree level ----------------
__global__ __launch_bounds__(128) void compose(int level) {
    const int p = blockIdx.y, n = blockIdx.x, m = threadIdx.x;
    const float2* A; const float2* B; float2* Cout;
    if (level == 0) {
        A = g_V + (2 * p + 1) * NDIM * NDIM;
        B = g_V + (2 * p) * NDIM * NDIM;
        Cout = g_W + p * NDIM * NDIM;
    } else {
        A = g_W + (2 * p + 1) * NDIM * NDIM;
        B = g_W + (2 * p) * NDIM * NDIM;
        Cout = g_Y + p * NDIM * NDIM;
    }
    __shared__ float2 arow[NDIM];
    arow[m] = A[n * NDIM + m];
    __syncthreads();
    float cr = 0.f, ci = 0.f;
    #pragma unroll 8
    for (int k = 0; k < NDIM; ++k) {
        const float2 b = B[k * NDIM + m];
        const float2 a = arow[k];
        cr = fmaf(a.x, b.x, fmaf(-a.y, b.y, cr));
        ci = fmaf(a.x, b.y, fmaf( a.y, b.x, ci));
    }
    Cout[n * NDIM + m] = make_float2(cr, ci);
}

// ---------------- K4: final compose U = Y1*Y0, diag, emit packed bf16 ----------------
__global__ __launch_bounds__(128) void compose_final(const float* __restrict__ oph) {
    const int n = blockIdx.x, m = threadIdx.x;
    const float2* A = g_Y + NDIM * NDIM;   // Y1 (left)
    const float2* B = g_Y;                 // Y0 (right)
    __shared__ float2 arow[NDIM];
    arow[m] = A[n * NDIM + m];
    __syncthreads();
    float cr = 0.f, ci = 0.f;
    #pragma unroll 8
    for (int k = 0; k < NDIM; ++k) {
        const float2 b = B[k * NDIM + m];
        const float2 a = arow[k];
        cr = fmaf(a.x, b.x, fmaf(-a.y, b.y, cr));
        ci = fmaf(a.x, b.y, fmaf( a.y, b.x, ci));
    }
    float ds, dc;
    sincosf(oph[n], &ds, &dc);
    const float vr = fmaf(cr, dc, -ci * ds);
    const float vi = fmaf(cr, ds,  ci * dc);
    const int kg = m >> 3, e = m & 7;
    g_TB[(kg * NDIM + n) * 8 + e]        = f2bf(vr);
    g_TB[((16 + kg) * NDIM + n) * 8 + e] = f2bf(-vi);
    g_Ur[(kg * NDIM + n) * 8 + e] = f2bf(vr);
    g_Ui[(kg * NDIM + n) * 8 + e] = f2bf(vi);
}

// ---------------- K5a: real-output GEMM (out_size == B*N, f32 real part) ----------------
// 256 blocks x 256 threads (4 waves), 1 block/CU (128 KB LDS). Each wave
// streams 8 independent 16-row tiles: COALESCED f32 loads (1KB/inst,
// lane-contiguous) -> reg cvt bf16 -> ds_write into wave-PRIVATE XOR-
// swizzled dbuf (no in-loop barriers) -> ds_read_b128 fragments -> MFMA.
// Swizzle byte ^= (row&7)<<4 makes both the b128 fragment reads and the
// b64 stage writes near-conflict-free. Table [Ur|-Ui] (K=256) in LDS,
// layout identical to R5/R6 (verified, 0 bank conflicts).
#define XLOAD(G, R)                                                             \
    {                                                                           \
        const float4* sre_ = (const float4*)(xr + (size_t)(R) * NDIM);          \
        const float4* sim_ = (const float4*)(xi + (size_t)(R) * NDIM);          \
        _Pragma("unroll")                                                       \
        for (int p_ = 0; p_ < 8; ++p_) G[p_]     = sre_[p_ * 64 + lane];        \
        _Pragma("unroll")                                                       \
        for (int p_ = 0; p_ < 8; ++p_) G[8 + p_] = sim_[p_ * 64 + lane];        \
    }

#define XSTAGE(G, bufp)                                                         \
    {                                                                           \
        _Pragma("unroll")                                                       \
        for (int p_ = 0; p_ < 8; ++p_) {                                        \
            const int r_ = 2 * p_ + lh;                                         \
            const int sw_ = (r_ & 7) << 4;                                      \
            uint2 v_;                                                           \
            v_.x = ((unsigned)f2bf(G[p_].y) << 16) | f2bf(G[p_].x);             \
            v_.y = ((unsigned)f2bf(G[p_].w) << 16) | f2bf(G[p_].z);             \
            *(uint2*)((bufp) + r_ * 512 + ((l32 * 8) ^ sw_)) = v_;              \
            v_.x = ((unsigned)f2bf(G[8 + p_].y) << 16) | f2bf(G[8 + p_].x);     \
            v_.y = ((unsigned)f2bf(G[8 + p_].w) << 16) | f2bf(G[8 + p_].z);     \
            *(uint2*)((bufp) + r_ * 512 + ((256 + l32 * 8) ^ sw_)) = v_;        \
        }                                                                       \
    }

#define FRAGS(fx, bufp)                                                         \
    {                                                                           \
        _Pragma("unroll")                                                       \
        for (int kc_ = 0; kc_ < 8; ++kc_)                                       \
            fx[kc_] = *(const bf16x8*)((bufp) + r15 * 512 +                     \
                        ((kc_ * 64 + kg4 * 16) ^ ((r15 & 7) << 4)));            \
    }

#define CSTORE(fx, R)                                                           \
    {                                                                           \
        const size_t orow_ = (size_t)((R) + r15) * NDIM;                        \
        _Pragma("unroll")                                                       \
        for (int nt_ = 0; nt_ < 8; ++nt_) {                                     \
            f32x4 a0_ = {0.f, 0.f, 0.f, 0.f};                                   \
            f32x4 a1_ = {0.f, 0.f, 0.f, 0.f};                                   \
            _Pragma("unroll")                                                   \
            for (int kc_ = 0; kc_ < 4; ++kc_)                                   \
                a0_ = __builtin_amdgcn_mfma_f32_16x16x32_bf16(                  \
                    smT[(kc_ * 4 + kg4) * NDIM + nt_ * 16 + r15], fx[kc_], a0_, 0, 0, 0); \
            _Pragma("unroll")                                                   \
            for (int kc_ = 4; kc_ < 8; ++kc_)                                   \
                a1_ = __builtin_amdgcn_mfma_f32_16x16x32_bf16(                  \
                    smT[(kc_ * 4 + kg4) * NDIM + nt_ * 16 + r15], fx[kc_], a1_, 0, 0, 0); \
            const f32x4 s_ = a0_ + a1_;                                         \
            *(float4*)(out + orow_ + nt_ * 16 + kg4 * 4) =                      \
                make_float4(s_[0], s_[1], s_[2], s_[3]);                        \
        }                                                                       \
    }

__global__ __launch_bounds__(256) void cmatmul0(const float* __restrict__ xr,
                                                const float* __restrict__ xi,
                                                float* __restrict__ out) {
    __shared__ bf16x8 smT[32 * NDIM];                 // 64 KB table
    __shared__ __align__(16) char smX[4][2][8192];    // 64 KB x dbuf (wave, phase)
    const int tid  = threadIdx.x;
    const int lane = tid & 63;
    const int w    = tid >> 6;
    const int r15  = lane & 15;
    const int kg4  = lane >> 4;
    const int l32  = lane & 31;
    const int lh   = lane >> 5;                       // row parity within pair

    // stage table (coalesced, once per block)
    {
        const bf16x8* gT = (const bf16x8*)g_TB;
        #pragma unroll
        for (int ch = 0; ch < 16; ++ch)
            smT[ch * 256 + tid] = gT[ch * 256 + tid];
    }

    const int Rw = blockIdx.x * 512 + w * 16;         // wave's tile-0 base row
    char* bufA = &smX[w][0][0];
    char* bufB = &smX[w][1][0];

    float4 GA[16], GB[16];
    XLOAD(GA, Rw)                                     // tile 0
    XLOAD(GB, Rw + 64)                                // tile 1
    __syncthreads();                                  // table ready
    XSTAGE(GA, bufA)                                  // tile 0 -> bufA

    for (int t = 0; t < 8; t += 2) {
        if (t + 2 < 8) XLOAD(GA, Rw + (t + 2) * 64)   // prefetch tile t+2
        {
            bf16x8 fx[8];
            FRAGS(fx, bufA)
            CSTORE(fx, Rw + t * 64)                   // compute tile t
        }
        XSTAGE(GB, bufB)                              // tile t+1 -> bufB
        if (t + 3 < 8) XLOAD(GB, Rw + (t + 3) * 64)   // prefetch tile t+3
        {
            bf16x8 fx[8];
            FRAGS(fx, bufB)
            CSTORE(fx, Rw + (t + 1) * 64)             // compute tile t+1
        }
        if (t + 2 < 8) XSTAGE(GA, bufA)               // tile t+2 -> bufA
    }
}

// ---------------- K5b: complex-output fallback (bf16 re,im pairs) ----------------
__global__ __launch_bounds__(256) void cmatmul1(const float* __restrict__ xr,
                                                const float* __restrict__ xi,
                                                ushort2* __restrict__ outp) {
    const int lane  = threadIdx.x & 63;
    const int w     = threadIdx.x >> 6;
    const int btile = blockIdx.x * 64 + w * 16;
    const int r15   = lane & 15;
    const int kg4   = lane >> 4;
    const int bload = btile + r15;

    const bf16x8* Ur = (const bf16x8*)g_Ur;
    const bf16x8* Ui = (const bf16x8*)g_Ui;
    const float* xrp = xr + (size_t)bload * NDIM;
    const float* xip = xi + (size_t)bload * NDIM;

    bf16x8 ar[4], ai[4], ain[4];
    #pragma unroll
    for (int kc = 0; kc < 4; ++kc) {
        const int k0 = kc * 32 + kg4 * 8;
        float4 rlo = *(const float4*)(xrp + k0);
        float4 rhi = *(const float4*)(xrp + k0 + 4);
        float4 ilo = *(const float4*)(xip + k0);
        float4 ihi = *(const float4*)(xip + k0 + 4);
        bf16x8 vr, vi, vn;
        vr[0] = (short)f2bf(rlo.x); vr[1] = (short)f2bf(rlo.y);
        vr[2] = (short)f2bf(rlo.z); vr[3] = (short)f2bf(rlo.w);
        vr[4] = (short)f2bf(rhi.x); vr[5] = (short)f2bf(rhi.y);
        vr[6] = (short)f2bf(rhi.z); vr[7] = (short)f2bf(rhi.w);
        vi[0] = (short)f2bf(ilo.x); vi[1] = (short)f2bf(ilo.y);
        vi[2] = (short)f2bf(ilo.z); vi[3] = (short)f2bf(ilo.w);
        vi[4] = (short)f2bf(ihi.x); vi[5] = (short)f2bf(ihi.y);
        vi[6] = (short)f2bf(ihi.z); vi[7] = (short)f2bf(ihi.w);
        #pragma unroll
        for (int e = 0; e < 8; ++e) vn[e] = (short)(vi[e] ^ 0x8000);
        ar[kc] = vr; ai[kc] = vi; ain[kc] = vn;
    }

    #pragma unroll
    for (int nt = 0; nt < 8; ++nt) {
        f32x4 accR = {0.f, 0.f, 0.f, 0.f};
        f32x4 accI = {0.f, 0.f, 0.f, 0.f};
        #pragma unroll
        for (int kc = 0; kc < 4; ++kc) {
            const int kg = kc * 4 + kg4;
            bf16x8 br = Ur[kg * NDIM + nt * 16 + r15];
            bf16x8 bi = Ui[kg * NDIM + nt * 16 + r15];
            accR = __builtin_amdgcn_mfma_f32_16x16x32_bf16(ar[kc],  br, accR, 0, 0, 0);
            accR = __builtin_amdgcn_mfma_f32_16x16x32_bf16(ain[kc], bi, accR, 0, 0, 0);
            accI = __builtin_amdgcn_mfma_f32_16x16x32_bf16(ar[kc],  bi, accI, 0, 0, 0);
            accI = __builtin_amdgcn_mfma_f32_16x16x32_bf16(ai[kc],  br, accI, 0, 0, 0);
        }
        const int n    = nt * 16 + r15;
        const int brow = btile + kg4 * 4;
        #pragma unroll
        for (int r = 0; r < 4; ++r)
            outp[(size_t)(brow + r) * NDIM + n] = make_ushort2(f2bf(accR[r]), f2bf(accI[r]));
    }
}

extern "C" void kernel_launch(void* const* d_in, const int* in_sizes, int n_in,
                              void* d_out, int out_size, void* d_ws, size_t ws_size,
                              hipStream_t stream) {
    const float* xr  = (const float*)d_in[0];
    const float* xi  = (const float*)d_in[1];
    const float* mzi = (const float*)d_in[2];
    const float* oph = (const float*)d_in[3];

    build_scan<<<dim3(4, NCHUNK), dim3(256), 0, stream>>>(mzi);
    compose<<<dim3(NDIM, 4), dim3(128), 0, stream>>>(0);
    compose<<<dim3(NDIM, 2), dim3(128), 0, stream>>>(1);
    compose_final<<<dim3(NDIM), dim3(128), 0, stream>>>(oph);
    if (out_size == BDIM * NDIM) {
        cmatmul0<<<dim3(BDIM / 512), dim3(256), 0, stream>>>(xr, xi, (float*)d_out);
    } else {
        cmatmul1<<<dim3(BDIM / 64), dim3(256), 0, stream>>>(xr, xi, (ushort2*)d_out);
    }
}

// Round 8
// 122.720 us; speedup vs baseline: 1.1688x; 1.1688x over previous
//
#include <hip/hip_runtime.h>
#include <hip/hip_bf16.h>

#define NDIM 128
#define BDIM 131072
#define NMZI 8128                       // 128*127/2
#define NCHUNK 8
#define CSTEP (NMZI / NCHUNK)           // 1016 steps per chunk
#define NJG 8                           // j-groups per block (scan groups)
#define NCOL 32                         // columns per block
#define NLOC 16                         // max local scan length
static constexpr float CC = 0.70710678118654752440f;  // sqrt(0.5)

typedef __attribute__((ext_vector_type(8))) short bf16x8;
typedef __attribute__((ext_vector_type(4))) float f32x4;

// Static device scratch (d_ws size unknown -> don't touch it)
__device__ __align__(16) float2         g_V[NCHUNK * NDIM * NDIM];  // chunk partial unitaries
__device__ __align__(16) float2         g_W[4 * NDIM * NDIM];       // compose level 1
__device__ __align__(16) float2         g_Y[2 * NDIM * NDIM];       // compose level 2
// Packed K=256 table for real-output GEMM: kg2<16 -> Ur[k=kg2*8+e][n]; kg2>=16 -> -Ui
__device__ __align__(16) unsigned short g_TB[32 * NDIM * 8];        // 64 KB
// Separate tables for the (unlikely) complex-interleaved output mode
__device__ __align__(16) unsigned short g_Ur[16 * NDIM * 8];
__device__ __align__(16) unsigned short g_Ui[16 * NDIM * 8];

__device__ inline unsigned short f2bf(float f) {
    union { __hip_bfloat16 h; unsigned short u; } cv;
    cv.h = __float2bfloat16(f);
    return cv.u;
}

// ---------------- K2: build chunk partial unitaries (affine-scan) ----------------
__global__ __launch_bounds__(256) void build_scan(const float* __restrict__ mzi) {
    __shared__ float2 Usm[NDIM][NCOL];        // 32 KB
    __shared__ float4 phs[CSTEP];             // 16.25 KB
    __shared__ float4 comp[NJG][NCOL];        // 4 KB
    const int tid   = threadIdx.x;
    const int c     = tid & 31;
    const int g     = tid >> 5;
    const int col0  = blockIdx.x * NCOL;
    const int chunk = blockIdx.y;
    const int s0 = chunk * CSTEP, s1 = s0 + CSTEP;

    for (int k = g; k < NDIM; k += NJG)
        Usm[k][c] = make_float2((k == col0 + c) ? 1.f : 0.f, 0.f);
    const float2* mzp = (const float2*)mzi;   // (theta, phi) pairs
    for (int t = tid; t < CSTEP; t += 256) {
        const float2 mz = mzp[s0 + t];
        float sp, cp, st, ct;
        sincosf(mz.y, &sp, &cp);              // phi
        sincosf(mz.x, &st, &ct);              // theta
        phs[t] = make_float4(cp, sp, CC * ct, CC * st);
    }
    __syncthreads();

    int i = 0, base = 0;
    while (base + (NDIM - 1 - i) <= s0) { base += NDIM - 1 - i; ++i; }

    int s = s0;
    while (s < s1) {
        const int cnt  = NDIM - 1 - i;
        const int jA   = i + 1 + (s - base);
        const int L    = min(s1, base + cnt) - s;
        const int nloc = (L + NJG - 1) >> 3;
        const int myBeg = g * nloc;
        const int myN   = max(0, min(nloc, L - myBeg));
        const int pbase = s - s0;

        const float2 r0 = Usm[i][c];          // read BEFORE barrier

        float2 treg[NLOC];
        float2 qth[NLOC];
        float  A = 1.f;
        float2 Bc = make_float2(0.f, 0.f);
        #pragma unroll
        for (int kk = 0; kk < NLOC; ++kk) {
            if (kk < myN) {
                const int off = myBeg + kk;
                const float4 q  = phs[pbase + off];
                const float2 rj = Usm[jA + off][c];
                const float tr = fmaf(q.x, rj.x, -q.y * rj.y);
                const float ti = fmaf(q.x, rj.y,  q.y * rj.x);
                treg[kk] = make_float2(tr, ti);
                qth[kk]  = make_float2(q.z, q.w);
                Bc.x = CC * (Bc.x + tr);
                Bc.y = CC * (Bc.y + ti);
                A *= CC;
            }
        }
        comp[g][c] = make_float4(A, Bc.x, Bc.y, 0.f);
        __syncthreads();

        float2 r = r0;
        for (int h = 0; h < g; ++h) {
            const float4 cm = comp[h][c];
            r.x = fmaf(cm.x, r.x, cm.y);
            r.y = fmaf(cm.x, r.y, cm.z);
        }

        #pragma unroll
        for (int kk = 0; kk < NLOC; ++kk) {
            if (kk < myN) {
                const float2 t = treg[kk];
                const float2 q = qth[kk];
                const float dr = r.x - t.x, di = r.y - t.y;
                const float njx = fmaf(q.x, dr, -q.y * di);
                const float njy = fmaf(q.x, di,  q.y * dr);
                Usm[jA + myBeg + kk][c] = make_float2(njx, njy);
                r.x = CC * (r.x + t.x);
                r.y = CC * (r.y + t.y);
            }
        }
        if (myN > 0 && (myBeg + myN == L))
            Usm[i][c] = r;
        __syncthreads();

        s += L;
        if (s == base + cnt) { base += cnt; ++i; }
    }

    float2* Vp = g_V + chunk * NDIM * NDIM;
    for (int k = g; k < NDIM; k += NJG)
        Vp[k * NDIM + col0 + c] = Usm[k][c];
}

// ---------------- K3: compose tree level ----------------
__global__ __launch_bounds__(128) void compose(int level) {
    const int p = blockIdx.y, n = blockIdx.x, m = threadIdx.x;
    const float2* A; const float2* B; float2* Cout;
    if (level == 0) {
        A = g_V + (2 * p + 1) * NDIM * NDIM;
        B = g_V + (2 * p) * NDIM * NDIM;
        Cout = g_W + p * NDIM * NDIM;
    } else {
        A = g_W + (2 * p + 1) * NDIM * NDIM;
        B = g_W + (2 * p) * NDIM * NDIM;
        Cout = g_Y + p * NDIM * NDIM;
    }
    __shared__ float2 arow[NDIM];
    arow[m] = A[n * NDIM + m];
    __syncthreads();
    float cr = 0.f, ci = 0.f;
    #pragma unroll 8
    for (int k = 0; k < NDIM; ++k) {
        const float2 b = B[k * NDIM + m];
        const float2 a = arow[k];
        cr = fmaf(a.x, b.x, fmaf(-a.y, b.y, cr));
        ci = fmaf(a.x, b.y, fmaf( a.y, b.x, ci));
    }
    Cout[n * NDIM + m] = make_float2(cr, ci);
}

// ---------------- K4: final compose U = Y1*Y0, diag, emit packed bf16 ----------------
__global__ __launch_bounds__(128) void compose_final(const float* __restrict__ oph) {
    const int n = blockIdx.x, m = threadIdx.x;
    const float2* A = g_Y + NDIM * NDIM;   // Y1 (left)
    const float2* B = g_Y;                 // Y0 (right)
    __shared__ float2 arow[NDIM];
    arow[m] = A[n * NDIM + m];
    __syncthreads();
    float cr = 0.f, ci = 0.f;
    #pragma unroll 8
    for (int k = 0; k < NDIM; ++k) {
        const float2 b = B[k * NDIM + m];
        const float2 a = arow[k];
        cr = fmaf(a.x, b.x, fmaf(-a.y, b.y, cr));
        ci = fmaf(a.x, b.y, fmaf( a.y, b.x, ci));
    }
    float ds, dc;
    sincosf(oph[n], &ds, &dc);
    const float vr = fmaf(cr, dc, -ci * ds);
    const float vi = fmaf(cr, ds,  ci * dc);
    const int kg = m >> 3, e = m & 7;
    g_TB[(kg * NDIM + n) * 8 + e]        = f2bf(vr);
    g_TB[((16 + kg) * NDIM + n) * 8 + e] = f2bf(-vi);
    g_Ur[(kg * NDIM + n) * 8 + e] = f2bf(vr);
    g_Ui[(kg * NDIM + n) * 8 + e] = f2bf(vi);
}

// ---------------- K5a: real-output GEMM (out_size == B*N, f32 real part) ----------------
// 2048 blocks x 256 threads (4 waves); wave owns ONE 16-row tile.
// (1) Coalesced global f32 loads: lane i reads base+i*16B (1KB/instr).
// (2) reg cvt f32->bf16, ds_write_b64 into wave-PRIVATE 8KB LDS buffer with
//     XOR swizzle byte^=(row&7)<<4  -> ds_read_b128 fragments conflict-free.
//     Wave-local only => ZERO barriers; LDS 32KB/block keeps occupancy high.
// (3) Table [Ur|-Ui] (K=256) read from global (L2-resident; R4 showed
//     table-from-L2 == table-from-LDS perf) so LDS stays small.
// MFMA/store layout identical to the verified R4/R6 kernels.
__global__ __launch_bounds__(256) void cmatmul0(const float* __restrict__ xr,
                                                const float* __restrict__ xi,
                                                float* __restrict__ out) {
    __shared__ __align__(16) char smX[4][8192];   // per-wave bf16 tile [16 rows][512B]
    const int tid  = threadIdx.x;
    const int lane = tid & 63;
    const int w    = tid >> 6;
    const int r15  = lane & 15;
    const int kg4  = lane >> 4;
    const int l31  = lane & 31;
    const int lh   = lane >> 5;
    const int R    = blockIdx.x * 64 + w * 16;    // wave's tile base row

    // (1) fully-coalesced tile load: 16 instr x 1KB contiguous
    const float4* sre = (const float4*)(xr + (size_t)R * NDIM);
    const float4* sim = (const float4*)(xi + (size_t)R * NDIM);
    float4 G[16];
    #pragma unroll
    for (int p = 0; p < 8; ++p) G[p]     = sre[p * 64 + lane];
    #pragma unroll
    for (int p = 0; p < 8; ++p) G[8 + p] = sim[p * 64 + lane];

    // (2) convert + swizzled LDS stage (wave-private, no barrier)
    char* buf = &smX[w][0];
    #pragma unroll
    for (int p = 0; p < 8; ++p) {
        const int row = 2 * p + lh;
        const int swz = (row & 7) << 4;
        uint2 v;
        v.x = ((unsigned)f2bf(G[p].y) << 16) | f2bf(G[p].x);
        v.y = ((unsigned)f2bf(G[p].w) << 16) | f2bf(G[p].z);
        *(uint2*)(buf + row * 512 + ((l31 * 8) ^ swz)) = v;
        v.x = ((unsigned)f2bf(G[8 + p].y) << 16) | f2bf(G[8 + p].x);
        v.y = ((unsigned)f2bf(G[8 + p].w) << 16) | f2bf(G[8 + p].z);
        *(uint2*)(buf + row * 512 + 256 + ((l31 * 8) ^ swz)) = v;
    }

    // fragments: lane (kg4,r15) <- row r15, k = kc*32 + kg4*8 .. +7
    bf16x8 fx[8];
    const int rswz = (r15 & 7) << 4;
    #pragma unroll
    for (int kc = 0; kc < 8; ++kc) {
        const int off = (((kc & 3) * 64 + kg4 * 16) ^ rswz) + ((kc >= 4) ? 256 : 0);
        fx[kc] = *(const bf16x8*)(buf + r15 * 512 + off);
    }

    // (3) MFMA: A = table fragment (rows = n), B = x fragment (cols = b-row)
    const bf16x8* gT = (const bf16x8*)g_TB;
    const size_t orow = (size_t)(R + r15) * NDIM;
    #pragma unroll
    for (int nt = 0; nt < 8; ++nt) {
        f32x4 a0 = {0.f, 0.f, 0.f, 0.f};
        f32x4 a1 = {0.f, 0.f, 0.f, 0.f};
        #pragma unroll
        for (int kc = 0; kc < 4; ++kc)
            a0 = __builtin_amdgcn_mfma_f32_16x16x32_bf16(
                gT[(kc * 4 + kg4) * NDIM + nt * 16 + r15], fx[kc], a0, 0, 0, 0);
        #pragma unroll
        for (int kc = 4; kc < 8; ++kc)
            a1 = __builtin_amdgcn_mfma_f32_16x16x32_bf16(
                gT[(kc * 4 + kg4) * NDIM + nt * 16 + r15], fx[kc], a1, 0, 0, 0);
        const f32x4 s = a0 + a1;
        *(float4*)(out + orow + nt * 16 + kg4 * 4) =
            make_float4(s[0], s[1], s[2], s[3]);
    }
}

// ---------------- K5b: complex-output fallback (bf16 re,im pairs) ----------------
__global__ __launch_bounds__(256) void cmatmul1(const float* __restrict__ xr,
                                                const float* __restrict__ xi,
                                                ushort2* __restrict__ outp) {
    const int lane  = threadIdx.x & 63;
    const int w     = threadIdx.x >> 6;
    const int btile = blockIdx.x * 64 + w * 16;
    const int r15   = lane & 15;
    const int kg4   = lane >> 4;
    const int bload = btile + r15;

    const bf16x8* Ur = (const bf16x8*)g_Ur;
    const bf16x8* Ui = (const bf16x8*)g_Ui;
    const float* xrp = xr + (size_t)bload * NDIM;
    const float* xip = xi + (size_t)bload * NDIM;

    bf16x8 ar[4], ai[4], ain[4];
    #pragma unroll
    for (int kc = 0; kc < 4; ++kc) {
        const int k0 = kc * 32 + kg4 * 8;
        float4 rlo = *(const float4*)(xrp + k0);
        float4 rhi = *(const float4*)(xrp + k0 + 4);
        float4 ilo = *(const float4*)(xip + k0);
        float4 ihi = *(const float4*)(xip + k0 + 4);
        bf16x8 vr, vi, vn;
        vr[0] = (short)f2bf(rlo.x); vr[1] = (short)f2bf(rlo.y);
        vr[2] = (short)f2bf(rlo.z); vr[3] = (short)f2bf(rlo.w);
        vr[4] = (short)f2bf(rhi.x); vr[5] = (short)f2bf(rhi.y);
        vr[6] = (short)f2bf(rhi.z); vr[7] = (short)f2bf(rhi.w);
        vi[0] = (short)f2bf(ilo.x); vi[1] = (short)f2bf(ilo.y);
        vi[2] = (short)f2bf(ilo.z); vi[3] = (short)f2bf(ilo.w);
        vi[4] = (short)f2bf(ihi.x); vi[5] = (short)f2bf(ihi.y);
        vi[6] = (short)f2bf(ihi.z); vi[7] = (short)f2bf(ihi.w);
        #pragma unroll
        for (int e = 0; e < 8; ++e) vn[e] = (short)(vi[e] ^ 0x8000);
        ar[kc] = vr; ai[kc] = vi; ain[kc] = vn;
    }

    #pragma unroll
    for (int nt = 0; nt < 8; ++nt) {
        f32x4 accR = {0.f, 0.f, 0.f, 0.f};
        f32x4 accI = {0.f, 0.f, 0.f, 0.f};
        #pragma unroll
        for (int kc = 0; kc < 4; ++kc) {
            const int kg = kc * 4 + kg4;
            bf16x8 br = Ur[kg * NDIM + nt * 16 + r15];
            bf16x8 bi = Ui[kg * NDIM + nt * 16 + r15];
            accR = __builtin_amdgcn_mfma_f32_16x16x32_bf16(ar[kc],  br, accR, 0, 0, 0);
            accR = __builtin_amdgcn_mfma_f32_16x16x32_bf16(ain[kc], bi, accR, 0, 0, 0);
            accI = __builtin_amdgcn_mfma_f32_16x16x32_bf16(ar[kc],  bi, accI, 0, 0, 0);
            accI = __builtin_amdgcn_mfma_f32_16x16x32_bf16(ai[kc],  br, accI, 0, 0, 0);
        }
        const int n    = nt * 16 + r15;
        const int brow = btile + kg4 * 4;
        #pragma unroll
        for (int r = 0; r < 4; ++r)
            outp[(size_t)(brow + r) * NDIM + n] = make_ushort2(f2bf(accR[r]), f2bf(accI[r]));
    }
}

extern "C" void kernel_launch(void* const* d_in, const int* in_sizes, int n_in,
                              void* d_out, int out_size, void* d_ws, size_t ws_size,
                              hipStream_t stream) {
    const float* xr  = (const float*)d_in[0];
    const float* xi  = (const float*)d_in[1];
    const float* mzi = (const float*)d_in[2];
    const float* oph = (const float*)d_in[3];

    build_scan<<<dim3(4, NCHUNK), dim3(256), 0, stream>>>(mzi);
    compose<<<dim3(NDIM, 4), dim3(128), 0, stream>>>(0);
    compose<<<dim3(NDIM, 2), dim3(128), 0, stream>>>(1);
    compose_final<<<dim3(NDIM), dim3(128), 0, stream>>>(oph);
    if (out_size == BDIM * NDIM) {
        cmatmul0<<<dim3(BDIM / 64), dim3(256), 0, stream>>>(xr, xi, (float*)d_out);
    } else {
        cmatmul1<<<dim3(BDIM / 64), dim3(256), 0, stream>>>(xr, xi, (ushort2*)d_out);
    }
}